// Round 8
// baseline (301.883 us; speedup 1.0000x reference)
//
#include <hip/hip_runtime.h>

#define TAU 0.02f

constexpr int Bc = 8, Cc = 64, Hc = 256, Wc = 256;
constexpr int R   = 4;               // rows per pipeline step
constexpr int TB  = 16;              // steps per block (TB*R = 64 rows per block)
constexpr int RB  = 16;              // ring rows: 16*256*4 = 16384 B
constexpr int RBF = RB * Wc;         // ring size in floats (4096, pow2)

__device__ __forceinline__ void coordf(float g, float shift, int n,
                                       int& i0, int& i1, float& w) {
    // exact reference semantics
    float p = (g + shift + 1.0f) * (0.5f * (float)(n - 1));
    p = fminf(fmaxf(p, 0.0f), (float)(n - 1));
    float f = floorf(p);
    w  = p - f;
    i0 = (int)f;
    i1 = min(i0 + 1, n - 1);
}

// clamp-adjusted pair: taps always (m, m+1); weight 1.0 when i0 clamped to n-1.
// Guarantees m in [0, n-2].
__device__ __forceinline__ void coord_adj(float g, float shift, int n,
                                          int& m, float& w) {
    int i0, i1; float ww;
    coordf(g, shift, n, i0, i1, ww);
    const bool top = (i0 == n - 1);
    m = top ? n - 2 : i0;
    w = top ? 1.0f  : ww;
}

__device__ __forceinline__ float gy_of(int i) {
    return fmaf((float)i, 2.0f / 255.0f, -1.0f);   // validated (prev session)
}

__device__ __forceinline__ float rdlane_f(float v, int lane) {
    return __int_as_float(__builtin_amdgcn_readlane(__float_as_int(v), lane));
}

__device__ __forceinline__ int slot_of(int row) {   // row in [-4, Hc+7]; RB pow2
    return row & (RB - 1);                          // two's-complement AND handles negatives
}

// async global -> LDS, 16 B per lane (one wave stages one full 256-float row)
__device__ __forceinline__ void gload_lds16(const float* g, float* l) {
    __builtin_amdgcn_global_load_lds(
        (const __attribute__((address_space(1))) void*)g,
        (__attribute__((address_space(3))) void*)l,
        16, 0, 0);
}

__global__ __launch_bounds__(256, 8) void remizov_ring(
    const float* __restrict__ x,
    const float* __restrict__ th_a,
    const float* __restrict__ th_bx,
    const float* __restrict__ th_by,
    const float* __restrict__ th_c,
    const float* __restrict__ base_gx,
    const float* __restrict__ base_gy,
    float* __restrict__ out)
{
    __shared__ float tile[RBF];   // 16 KB ring

    const int j    = threadIdx.x;
    const int lane = j & 63;
    const int wv   = j >> 6;
    const int base = blockIdx.x * (TB * R);   // 0, 64, 128, 192
    const int c    = blockIdx.y;
    const int b    = blockIdx.z;

    // ---- per-channel constants ----
    const float a  = log1pf(expf(th_a[c]));   // softplus
    const float s  = sqrtf(a * TAU + 1e-8f);
    const float dx = th_bx[c] * TAU;
    const float dy = th_by[c] * TAU;
    const float tc = th_c[c]  * TAU;

    // ---- x metadata: row-invariant, clamp-adjusted contiguous pairs ----
    const float gxv = base_gx[j];
    int xp, xn, xc; float wxp, wxn, wxc;
    coord_adj(gxv,  s + dx, Wc, xp, wxp);
    coord_adj(gxv, -s + dx, Wc, xn, wxn);
    coord_adj(gxv,      dx, Wc, xc, wxc);

    const size_t plane = (size_t)(b * Cc + c) * (size_t)(Hc * Wc);
    const float* __restrict__ P = x + plane;

    // ---- staging: nrows rows starting at row a (nrows % 4 == 0) ----
    // wave w stages row a+4k+w; lanes cover 16 B each -> one row per instr per wave.
    auto stage = [&](int a, int nrows) {
        for (int k = 0; k < (nrows >> 2); ++k) {
            const int row  = a + 4 * k + wv;
            const int srow = min(max(row, 0), Hc - 1);     // clamp src; junk slots never read
            gload_lds16(P + (size_t)srow * Wc + lane * 4,
                        &tile[slot_of(row) * Wc + lane * 4]);
        }
    };

    stage(base - 4, 12);      // prologue: window [base-4, base+7] for step 0
    __syncthreads();          // drains vmcnt -> staged rows visible

    const int lane4 = j & 3;

    for (int t = 0; t < TB; ++t) {
        const int i0 = base + t * R;

        // issue next strip EARLY: lands during this step's compute
        if (t < TB - 1) stage(i0 + 8, 4);

        // ---- per-lane exact y metadata: lane (j&3) owns row i0+(j&3) ----
        int   m_yc, m_yp, m_yn;
        float m_wc, m_wp, m_wn;
        {
            const float gyr = gy_of(i0 + lane4);
            coord_adj(gyr,      dy, Hc, m_yc, m_wc);
            coord_adj(gyr,  s + dy, Hc, m_yp, m_wp);
            coord_adj(gyr, -s + dy, Hc, m_yn, m_wn);
        }

        const int acr = __builtin_amdgcn_readlane(m_yc, 2) - (i0 + 2);
        const int apr = __builtin_amdgcn_readlane(m_yp, 2) - (i0 + 2);
        const int anr = __builtin_amdgcn_readlane(m_yn, 2) - (i0 + 2);
        const float wc = rdlane_f(m_wc, 2);
        const float wp = rdlane_f(m_wp, 2);
        const float wn = rdlane_f(m_wn, 2);

        // conformity (uniform stencil) and window coverage (taps m, m+1 in [i0-4, i0+7])
        bool okc = (m_yc == i0 + lane4 + acr) &&
                   (m_yp == i0 + lane4 + apr) &&
                   (m_yn == i0 + lane4 + anr);
        bool okw = (m_yc >= i0 - 4) && (m_yc <= i0 + 6) &&
                   (m_yp >= i0 - 4) && (m_yp <= i0 + 6) &&
                   (m_yn >= i0 - 4) && (m_yn <= i0 + 6);
        const unsigned long long cm = __ballot(okc);
        const unsigned long long wm = __ballot(okw);

        float* __restrict__ dst = out + plane + (size_t)i0 * Wc + j;

        auto ldS2 = [&](int o) -> float {      // h+ + h- at ring float-offset o
            float a0 = tile[o + xp], a1 = tile[o + xp + 1];
            float b0 = tile[o + xn], b1 = tile[o + xn + 1];
            return (a0 + wxp * (a1 - a0)) + (b0 + wxn * (b1 - b0));
        };
        auto ldC2 = [&](int o) -> float {      // center column
            float a0 = tile[o + xc], a1 = tile[o + xc + 1];
            return a0 + wxc * (a1 - a0);
        };

        if (wm == 0xFFFFFFFFFFFFFFFFull) {
            if (cm == 0xFFFFFFFFFFFFFFFFull) {
                // ============ fast uniform path: rolling ring streams ============
                int oS = slot_of(i0 + acr) * Wc;
                int oP = slot_of(i0 + apr) * Wc;
                int oN = slot_of(i0 + anr) * Wc;
                int oX = slot_of(i0)       * Wc;
                auto nx = [&](int& o) { o = (o + Wc) & (RBF - 1); };

                float Sc0 = ldS2(oS); nx(oS); float Sc1 = ldS2(oS);
                float Wp0 = ldC2(oP); nx(oP); float Wp1 = ldC2(oP);
                float Wn0 = ldC2(oN); nx(oN); float Wn1 = ldC2(oN);

#pragma unroll
                for (int r = 0; r < R; ++r) {
                    float v01 = Sc0 + wc * (Sc1 - Sc0);
                    float v2  = Wp0 + wp * (Wp1 - Wp0);
                    float v3  = Wn0 + wn * (Wn1 - Wn0);
                    float xv  = tile[oX + j];
                    dst[(size_t)(r << 8)] = 0.25f * (v01 + v2 + v3) + tc * xv;
                    nx(oX);
                    if (r < R - 1) {
                        Sc0 = Sc1; nx(oS); Sc1 = ldS2(oS);
                        Wp0 = Wp1; nx(oP); Wp1 = ldC2(oP);
                        Wn0 = Wn1; nx(oN); Wn1 = ldC2(oN);
                    }
                }
            } else {
                // ============ exact ring path (borders / floor flips) ============
                for (int r = 0; r < R; ++r) {
                    const float gyr = gy_of(i0 + r);
                    int yc, yp, yn; float wyc, wyp, wyn;
                    coord_adj(gyr,      dy, Hc, yc, wyc);
                    coord_adj(gyr,  s + dy, Hc, yp, wyp);
                    coord_adj(gyr, -s + dy, Hc, yn, wyn);
                    float v01 = (1.0f - wyc) * ldS2(slot_of(yc) * Wc)
                              +         wyc  * ldS2(slot_of(yc + 1) * Wc);
                    float v2  = (1.0f - wyp) * ldC2(slot_of(yp) * Wc)
                              +         wyp  * ldC2(slot_of(yp + 1) * Wc);
                    float v3  = (1.0f - wyn) * ldC2(slot_of(yn) * Wc)
                              +         wyn  * ldC2(slot_of(yn + 1) * Wc);
                    float xv  = tile[slot_of(i0 + r) * Wc + j];
                    dst[(size_t)(r << 8)] = 0.25f * (v01 + v2 + v3) + tc * xv;
                }
            }
        } else {
            // ============ direct-global exact (shift beyond window; ~6+ sigma) ============
            for (int r = 0; r < R; ++r) {
                const float gyr = gy_of(i0 + r);
                int yc, yp, yn; float wyc, wyp, wyn;
                coord_adj(gyr,      dy, Hc, yc, wyc);
                coord_adj(gyr,  s + dy, Hc, yp, wyp);
                coord_adj(gyr, -s + dy, Hc, yn, wyn);
                auto gS = [&](int y) -> float {
                    const float* rp = P + (size_t)y * Wc;
                    float a0 = rp[xp], a1 = rp[xp + 1];
                    float b0 = rp[xn], b1 = rp[xn + 1];
                    return (a0 + wxp * (a1 - a0)) + (b0 + wxn * (b1 - b0));
                };
                auto gC = [&](int y) -> float {
                    const float* rp = P + (size_t)y * Wc;
                    float a0 = rp[xc], a1 = rp[xc + 1];
                    return a0 + wxc * (a1 - a0);
                };
                float v01 = (1.0f - wyc) * gS(yc) + wyc * gS(yc + 1);
                float v2  = (1.0f - wyp) * gC(yp) + wyp * gC(yp + 1);
                float v3  = (1.0f - wyn) * gC(yn) + wyn * gC(yn + 1);
                float xv  = P[(size_t)(i0 + r) * Wc + j];
                dst[(size_t)(r << 8)] = 0.25f * (v01 + v2 + v3) + tc * xv;
            }
        }

        __syncthreads();   // drains vmcnt (stage loads landed) + barrier for slot reuse
    }
}

extern "C" void kernel_launch(void* const* d_in, const int* in_sizes, int n_in,
                              void* d_out, int out_size, void* d_ws, size_t ws_size,
                              hipStream_t stream)
{
    const float* x       = (const float*)d_in[0];
    const float* th_a    = (const float*)d_in[1];
    const float* th_bx   = (const float*)d_in[2];
    const float* th_by   = (const float*)d_in[3];
    const float* th_c    = (const float*)d_in[4];
    const float* base_gx = (const float*)d_in[5];
    const float* base_gy = (const float*)d_in[6];
    float* out = (float*)d_out;

    dim3 grid(Hc / (TB * R), Cc, Bc);   // (4, 64, 8) = 2048 blocks = 8/CU exactly
    dim3 block(Wc);
    remizov_ring<<<grid, block, 0, stream>>>(x, th_a, th_bx, th_by, th_c,
                                             base_gx, base_gy, out);
}

// Round 12
// 284.011 us; speedup vs baseline: 1.0629x; 1.0629x over previous
//
#include <hip/hip_runtime.h>

#define TAU 0.02f

constexpr int Bc = 8, Cc = 64, Hc = 256, Wc = 256;
constexpr int RS  = 16;              // rows per pipeline step (two 8-row halves)
constexpr int TB  = 8;               // steps per block (TB*RS = 128 rows per block)
constexpr int RB  = 40;              // ring rows: 40*256*4 = 40960 B; 4 blocks/CU = 160 KB exact
constexpr int RBF = RB * Wc;         // ring size in floats

__device__ __forceinline__ void coordf(float g, float shift, int n,
                                       int& i0, int& i1, float& w) {
    // exact reference semantics
    float p = (g + shift + 1.0f) * (0.5f * (float)(n - 1));
    p = fminf(fmaxf(p, 0.0f), (float)(n - 1));
    float f = floorf(p);
    w  = p - f;
    i0 = (int)f;
    i1 = min(i0 + 1, n - 1);
}

// clamp-adjusted pair: taps always (m, m+1); weight 1.0 when i0 clamped to n-1.
// Guarantees m in [0, n-2].
__device__ __forceinline__ void coord_adj(float g, float shift, int n,
                                          int& m, float& w) {
    int i0, i1; float ww;
    coordf(g, shift, n, i0, i1, ww);
    const bool top = (i0 == n - 1);
    m = top ? n - 2 : i0;
    w = top ? 1.0f  : ww;
}

__device__ __forceinline__ float gy_of(int i) {
    return fmaf((float)i, 2.0f / 255.0f, -1.0f);   // validated (prev session)
}

__device__ __forceinline__ float rdlane_f(float v, int lane) {
    return __int_as_float(__builtin_amdgcn_readlane(__float_as_int(v), lane));
}

__device__ __forceinline__ int slot_of(int row) {   // row in [-4, Hc+35]
    int m = row % RB;
    return (m < 0) ? m + RB : m;
}

// async global -> LDS, 16 B per lane (one wave stages one full 256-float row)
__device__ __forceinline__ void gload_lds16(const float* g, float* l) {
    __builtin_amdgcn_global_load_lds(
        (const __attribute__((address_space(1))) void*)g,
        (__attribute__((address_space(3))) void*)l,
        16, 0, 0);
}

__global__ __launch_bounds__(512, 8) void remizov_ring(
    const float* __restrict__ x,
    const float* __restrict__ th_a,
    const float* __restrict__ th_bx,
    const float* __restrict__ th_by,
    const float* __restrict__ th_c,
    const float* __restrict__ base_gx,
    const float* __restrict__ base_gy,
    float* __restrict__ out)
{
    __shared__ float tile[RBF];   // 40 KB ring

    const int tid   = threadIdx.x;
    const int j     = tid & 255;        // column
    const int h     = tid >> 8;         // row-half (0/1)
    const int lane  = tid & 63;         // lane within wave
    const int wv    = tid >> 6;         // wave id 0..7
    const int lane8 = tid & 7;
    const int base  = blockIdx.x * (TB * RS);   // 0 or 128
    const int c     = blockIdx.y;
    const int b     = blockIdx.z;

    // ---- per-channel constants ----
    const float a  = log1pf(expf(th_a[c]));   // softplus
    const float s  = sqrtf(a * TAU + 1e-8f);
    const float dx = th_bx[c] * TAU;
    const float dy = th_by[c] * TAU;
    const float tc = th_c[c]  * TAU;

    // ---- x metadata: row-invariant, clamp-adjusted contiguous pairs ----
    const float gxv = base_gx[j];
    int xp, xn, xc; float wxp, wxn, wxc;
    coord_adj(gxv,  s + dx, Wc, xp, wxp);
    coord_adj(gxv, -s + dx, Wc, xn, wxn);
    coord_adj(gxv,      dx, Wc, xc, wxc);

    const size_t plane = (size_t)(b * Cc + c) * (size_t)(Hc * Wc);
    const float* __restrict__ P = x + plane;

    // ---- staging: nrows rows starting at row a (nrows % 8 == 0) ----
    // wave w stages row a+8k+w; 64 lanes x 16 B cover one full row per instr.
    auto stage = [&](int a, int nrows) {
        for (int k = 0; k < (nrows >> 3); ++k) {
            const int row  = a + 8 * k + wv;
            const int srow = min(max(row, 0), Hc - 1);     // clamp src; junk slots never read
            gload_lds16(P + (size_t)srow * Wc + lane * 4,
                        &tile[slot_of(row) * Wc + lane * 4]);
        }
    };

    stage(base - 4, 24);      // prologue: window [base-4, base+19] for step 0
    __syncthreads();          // drains vmcnt -> staged rows visible

    for (int t = 0; t < TB; ++t) {
        const int i0    = base + t * RS;
        const int rbase = i0 + 8 * h;    // this half's first output row

        // issue next strip EARLY: lands during this step's compute
        if (t < TB - 1) stage(i0 + 20, 16);

        // ---- per-lane exact y metadata: lane (tid&7) owns row rbase+(tid&7) ----
        int   m_yc, m_yp, m_yn;
        float m_wc, m_wp, m_wn;
        {
            const float gyr = gy_of(rbase + lane8);
            coord_adj(gyr,      dy, Hc, m_yc, m_wc);
            coord_adj(gyr,  s + dy, Hc, m_yp, m_wp);
            coord_adj(gyr, -s + dy, Hc, m_yn, m_wn);
        }

        const int acr = __builtin_amdgcn_readlane(m_yc, 4) - (rbase + 4);
        const int apr = __builtin_amdgcn_readlane(m_yp, 4) - (rbase + 4);
        const int anr = __builtin_amdgcn_readlane(m_yn, 4) - (rbase + 4);
        const float wc = rdlane_f(m_wc, 4);
        const float wp = rdlane_f(m_wp, 4);
        const float wn = rdlane_f(m_wn, 4);

        // conformity (uniform stencil) and window coverage (taps m,m+1 in [i0-4, i0+19])
        bool okc = (m_yc == rbase + lane8 + acr) &&
                   (m_yp == rbase + lane8 + apr) &&
                   (m_yn == rbase + lane8 + anr);
        bool okw = (m_yc >= i0 - 4) && (m_yc <= i0 + 18) &&
                   (m_yp >= i0 - 4) && (m_yp <= i0 + 18) &&
                   (m_yn >= i0 - 4) && (m_yn <= i0 + 18);
        const unsigned long long cm = __ballot(okc);
        const unsigned long long wm = __ballot(okw);

        float* __restrict__ dst = out + plane + (size_t)rbase * Wc + j;

        auto ldS2 = [&](int o) -> float {      // h+ + h- at ring float-offset o
            float a0 = tile[o + xp], a1 = tile[o + xp + 1];
            float b0 = tile[o + xn], b1 = tile[o + xn + 1];
            return (a0 + wxp * (a1 - a0)) + (b0 + wxn * (b1 - b0));
        };
        auto ldC2 = [&](int o) -> float {      // center column
            float a0 = tile[o + xc], a1 = tile[o + xc + 1];
            return a0 + wxc * (a1 - a0);
        };

        if (wm == 0xFFFFFFFFFFFFFFFFull) {
            if (cm == 0xFFFFFFFFFFFFFFFFull) {
                // ============ fast uniform path: rolling ring streams ============
                int oS = slot_of(rbase + acr) * Wc;
                int oP = slot_of(rbase + apr) * Wc;
                int oN = slot_of(rbase + anr) * Wc;
                int oX = slot_of(rbase)       * Wc;
                auto nx = [&](int& o) { o += Wc; if (o >= RBF) o -= RBF; };

                float Sc0 = ldS2(oS); nx(oS); float Sc1 = ldS2(oS);
                float Wp0 = ldC2(oP); nx(oP); float Wp1 = ldC2(oP);
                float Wn0 = ldC2(oN); nx(oN); float Wn1 = ldC2(oN);

#pragma unroll
                for (int r = 0; r < 8; ++r) {
                    float v01 = Sc0 + wc * (Sc1 - Sc0);
                    float v2  = Wp0 + wp * (Wp1 - Wp0);
                    float v3  = Wn0 + wn * (Wn1 - Wn0);
                    float xv  = tile[oX + j];
                    dst[(size_t)(r << 8)] = 0.25f * (v01 + v2 + v3) + tc * xv;
                    nx(oX);
                    if (r < 7) {
                        Sc0 = Sc1; nx(oS); Sc1 = ldS2(oS);
                        Wp0 = Wp1; nx(oP); Wp1 = ldC2(oP);
                        Wn0 = Wn1; nx(oN); Wn1 = ldC2(oN);
                    }
                }
            } else {
                // ============ exact ring path (borders / floor flips) ============
                for (int r = 0; r < 8; ++r) {
                    const float gyr = gy_of(rbase + r);
                    int yc, yp, yn; float wyc, wyp, wyn;
                    coord_adj(gyr,      dy, Hc, yc, wyc);
                    coord_adj(gyr,  s + dy, Hc, yp, wyp);
                    coord_adj(gyr, -s + dy, Hc, yn, wyn);
                    float v01 = (1.0f - wyc) * ldS2(slot_of(yc) * Wc)
                              +         wyc  * ldS2(slot_of(yc + 1) * Wc);
                    float v2  = (1.0f - wyp) * ldC2(slot_of(yp) * Wc)
                              +         wyp  * ldC2(slot_of(yp + 1) * Wc);
                    float v3  = (1.0f - wyn) * ldC2(slot_of(yn) * Wc)
                              +         wyn  * ldC2(slot_of(yn + 1) * Wc);
                    float xv  = tile[slot_of(rbase + r) * Wc + j];
                    dst[(size_t)(r << 8)] = 0.25f * (v01 + v2 + v3) + tc * xv;
                }
            }
        } else {
            // ============ direct-global exact (shift beyond window; ~6+ sigma) ============
            for (int r = 0; r < 8; ++r) {
                const float gyr = gy_of(rbase + r);
                int yc, yp, yn; float wyc, wyp, wyn;
                coord_adj(gyr,      dy, Hc, yc, wyc);
                coord_adj(gyr,  s + dy, Hc, yp, wyp);
                coord_adj(gyr, -s + dy, Hc, yn, wyn);
                auto gS = [&](int y) -> float {
                    const float* rp = P + (size_t)y * Wc;
                    float a0 = rp[xp], a1 = rp[xp + 1];
                    float b0 = rp[xn], b1 = rp[xn + 1];
                    return (a0 + wxp * (a1 - a0)) + (b0 + wxn * (b1 - b0));
                };
                auto gC = [&](int y) -> float {
                    const float* rp = P + (size_t)y * Wc;
                    float a0 = rp[xc], a1 = rp[xc + 1];
                    return a0 + wxc * (a1 - a0);
                };
                float v01 = (1.0f - wyc) * gS(yc) + wyc * gS(yc + 1);
                float v2  = (1.0f - wyp) * gC(yp) + wyp * gC(yp + 1);
                float v3  = (1.0f - wyn) * gC(yn) + wyn * gC(yn + 1);
                float xv  = P[(size_t)(rbase + r) * Wc + j];
                dst[(size_t)(r << 8)] = 0.25f * (v01 + v2 + v3) + tc * xv;
            }
        }

        __syncthreads();   // drains vmcnt (stage loads landed) + barrier for slot reuse
    }
}

extern "C" void kernel_launch(void* const* d_in, const int* in_sizes, int n_in,
                              void* d_out, int out_size, void* d_ws, size_t ws_size,
                              hipStream_t stream)
{
    const float* x       = (const float*)d_in[0];
    const float* th_a    = (const float*)d_in[1];
    const float* th_bx   = (const float*)d_in[2];
    const float* th_by   = (const float*)d_in[3];
    const float* th_c    = (const float*)d_in[4];
    const float* base_gx = (const float*)d_in[5];
    const float* base_gy = (const float*)d_in[6];
    float* out = (float*)d_out;

    dim3 grid(Hc / (TB * RS), Cc, Bc);   // (2, 64, 8) = 1024 blocks = 4/CU, compact
    dim3 block(512);
    remizov_ring<<<grid, block, 0, stream>>>(x, th_a, th_bx, th_by, th_c,
                                             base_gx, base_gy, out);
}

// Round 13
// 256.001 us; speedup vs baseline: 1.1792x; 1.1094x over previous
//
#include <hip/hip_runtime.h>

#define TAU 0.02f

constexpr int Bc = 8, Cc = 64, Hc = 256, Wc = 256;
constexpr int R   = 8;               // rows per pipeline step
constexpr int TB  = 16;              // steps per block (TB*R = 128 rows per block)
constexpr int RB  = 32;              // pow2 ring rows: 32 KB; grid gives 4 blocks/CU
constexpr int RBF = RB * Wc;         // 8192 floats (pow2)

__device__ __forceinline__ void coordf(float g, float shift, int n,
                                       int& i0, int& i1, float& w) {
    // exact reference semantics
    float p = (g + shift + 1.0f) * (0.5f * (float)(n - 1));
    p = fminf(fmaxf(p, 0.0f), (float)(n - 1));
    float f = floorf(p);
    w  = p - f;
    i0 = (int)f;
    i1 = min(i0 + 1, n - 1);
}

// clamp-adjusted pair: taps always (m, m+1); weight 1.0 when i0 clamped to n-1.
// Guarantees m in [0, n-2].
__device__ __forceinline__ void coord_adj(float g, float shift, int n,
                                          int& m, float& w) {
    int i0, i1; float ww;
    coordf(g, shift, n, i0, i1, ww);
    const bool top = (i0 == n - 1);
    m = top ? n - 2 : i0;
    w = top ? 1.0f  : ww;
}

__device__ __forceinline__ float gy_of(int i) {
    return fmaf((float)i, 2.0f / 255.0f, -1.0f);   // validated (prev session)
}

__device__ __forceinline__ float rdlane_f(float v, int lane) {
    return __int_as_float(__builtin_amdgcn_readlane(__float_as_int(v), lane));
}

__device__ __forceinline__ int slot_of(int row) {   // ring slot; RB pow2
    return row & (RB - 1);                          // two's-complement AND handles negatives
}

// async global -> LDS, 16 B per lane (one wave stages one full 256-float row)
__device__ __forceinline__ void gload_lds16(const float* g, float* l) {
    __builtin_amdgcn_global_load_lds(
        (const __attribute__((address_space(1))) void*)g,
        (__attribute__((address_space(3))) void*)l,
        16, 0, 0);
}

__global__ __launch_bounds__(256, 4) void remizov_ring(
    const float* __restrict__ x,
    const float* __restrict__ th_a,
    const float* __restrict__ th_bx,
    const float* __restrict__ th_by,
    const float* __restrict__ th_c,
    const float* __restrict__ base_gx,
    const float* __restrict__ base_gy,
    float* __restrict__ out)
{
    __shared__ float tile[RBF];   // 32 KB ring

    const int j    = threadIdx.x;
    const int lane = j & 63;
    const int wv   = j >> 6;
    const int base = blockIdx.x * (TB * R);   // 0 or 128
    const int c    = blockIdx.y;
    const int b    = blockIdx.z;

    // ---- per-channel constants ----
    const float a  = log1pf(expf(th_a[c]));   // softplus
    const float s  = sqrtf(a * TAU + 1e-8f);
    const float dx = th_bx[c] * TAU;
    const float dy = th_by[c] * TAU;
    const float tc = th_c[c]  * TAU;

    // ---- x metadata: row-invariant, clamp-adjusted contiguous pairs ----
    const float gxv = base_gx[j];
    int xp, xn, xc; float wxp, wxn, wxc;
    coord_adj(gxv,  s + dx, Wc, xp, wxp);
    coord_adj(gxv, -s + dx, Wc, xn, wxn);
    coord_adj(gxv,      dx, Wc, xc, wxc);

    const size_t plane = (size_t)(b * Cc + c) * (size_t)(Hc * Wc);
    const float* __restrict__ P = x + plane;

    // ---- staging: nrows rows starting at row a (nrows % 4 == 0) ----
    // wave w stages row a+4k+w; 64 lanes x 16 B cover one full row per instr.
    auto stage = [&](int a, int nrows) {
        for (int k = 0; k < (nrows >> 2); ++k) {
            const int row  = a + 4 * k + wv;
            const int srow = min(max(row, 0), Hc - 1);     // clamp src; junk slots never read
            gload_lds16(P + (size_t)srow * Wc + lane * 4,
                        &tile[slot_of(row) * Wc + lane * 4]);
        }
    };

    stage(base - 4, 20);      // prologue: rows [base-4, base+15] (window for step 0)
    __syncthreads();          // drains vmcnt -> staged rows visible

    const int lane8 = j & 7;

    // ---- persistent rolling stream state (survives across steps) ----
    bool  live = false;
    int   l_acr = 0x7fffffff, l_apr = 0, l_anr = 0;
    int   oS = 0, oP = 0, oN = 0;
    float Sc0 = 0.f, Sc1 = 0.f, Wp0 = 0.f, Wp1 = 0.f, Wn0 = 0.f, Wn1 = 0.f;

    auto ldS2 = [&](int o) -> float {      // h+ + h- at ring float-offset o
        float a0 = tile[o + xp], a1 = tile[o + xp + 1];
        float b0 = tile[o + xn], b1 = tile[o + xn + 1];
        return (a0 + wxp * (a1 - a0)) + (b0 + wxn * (b1 - b0));
    };
    auto ldC2 = [&](int o) -> float {      // center column
        float a0 = tile[o + xc], a1 = tile[o + xc + 1];
        return a0 + wxc * (a1 - a0);
    };

    for (int t = 0; t < TB; ++t) {
        const int i0 = base + t * R;

        // issue next strip EARLY: lands during this step's compute.
        // strip [i0+13, i0+20]; window reads stay <= i0+12 (disjoint, race-free)
        if (t < TB - 1) stage(i0 + 13, 8);

        // ---- per-lane exact y metadata: lane (j&7) owns row i0+(j&7) ----
        int   m_yc, m_yp, m_yn;
        float m_wc, m_wp, m_wn;
        {
            const float gyr = gy_of(i0 + lane8);
            coord_adj(gyr,      dy, Hc, m_yc, m_wc);
            coord_adj(gyr,  s + dy, Hc, m_yp, m_wp);
            coord_adj(gyr, -s + dy, Hc, m_yn, m_wn);
        }

        const int acr = __builtin_amdgcn_readlane(m_yc, 4) - (i0 + 4);
        const int apr = __builtin_amdgcn_readlane(m_yp, 4) - (i0 + 4);
        const int anr = __builtin_amdgcn_readlane(m_yn, 4) - (i0 + 4);
        const float wc = rdlane_f(m_wc, 4);
        const float wp = rdlane_f(m_wp, 4);
        const float wn = rdlane_f(m_wn, 4);

        // conformity (uniform stencil); delta bound keeps every read (incl the
        // r=7 prefetch at row i0+9+delta) inside window [i0-4, i0+12]
        bool okc = (m_yc == i0 + lane8 + acr) &&
                   (m_yp == i0 + lane8 + apr) &&
                   (m_yn == i0 + lane8 + anr);
        const bool okd = (acr >= -4 && acr <= 3) &&
                         (apr >= -4 && apr <= 3) &&
                         (anr >= -4 && anr <= 3);
        // exact-ring coverage: taps m, m+1 within [i0-4, i0+12]
        bool okw = (m_yc >= i0 - 4) && (m_yc <= i0 + 11) &&
                   (m_yp >= i0 - 4) && (m_yp <= i0 + 11) &&
                   (m_yn >= i0 - 4) && (m_yn <= i0 + 11);
        const unsigned long long cm = __ballot(okc);
        const unsigned long long wm = __ballot(okw);

        float* __restrict__ dst = out + plane + (size_t)i0 * Wc + j;

        if (cm == 0xFFFFFFFFFFFFFFFFull && okd) {
            // ============ fast uniform path: persistent rolling streams ============
            if (!live || acr != l_acr || apr != l_apr || anr != l_anr) {
                l_acr = acr; l_apr = apr; l_anr = anr;
                oS = slot_of(i0 + acr) * Wc;
                Sc0 = ldS2(oS); oS = (oS + Wc) & (RBF - 1); Sc1 = ldS2(oS);
                oP = slot_of(i0 + apr) * Wc;
                Wp0 = ldC2(oP); oP = (oP + Wc) & (RBF - 1); Wp1 = ldC2(oP);
                oN = slot_of(i0 + anr) * Wc;
                Wn0 = ldC2(oN); oN = (oN + Wc) & (RBF - 1); Wn1 = ldC2(oN);
                live = true;
            }
            int oX = slot_of(i0) * Wc;

#pragma unroll
            for (int r = 0; r < R; ++r) {
                float v01 = Sc0 + wc * (Sc1 - Sc0);
                float v2  = Wp0 + wp * (Wp1 - Wp0);
                float v3  = Wn0 + wn * (Wn1 - Wn0);
                float xv  = tile[oX + j];
                dst[(size_t)(r << 8)] = 0.25f * (v01 + v2 + v3) + tc * xv;
                oX = (oX + Wc) & (RBF - 1);
                // advance EVERY row (incl r=7): leaves state = next step's warmup
                Sc0 = Sc1; oS = (oS + Wc) & (RBF - 1); Sc1 = ldS2(oS);
                Wp0 = Wp1; oP = (oP + Wc) & (RBF - 1); Wp1 = ldC2(oP);
                Wn0 = Wn1; oN = (oN + Wc) & (RBF - 1); Wn1 = ldC2(oN);
            }
        } else if (wm == 0xFFFFFFFFFFFFFFFFull) {
            // ============ exact ring path (borders / floor flips) ============
            live = false;
            for (int r = 0; r < R; ++r) {
                const float gyr = gy_of(i0 + r);
                int yc, yp, yn; float wyc, wyp, wyn;
                coord_adj(gyr,      dy, Hc, yc, wyc);
                coord_adj(gyr,  s + dy, Hc, yp, wyp);
                coord_adj(gyr, -s + dy, Hc, yn, wyn);
                float v01 = (1.0f - wyc) * ldS2(slot_of(yc) * Wc)
                          +         wyc  * ldS2(slot_of(yc + 1) * Wc);
                float v2  = (1.0f - wyp) * ldC2(slot_of(yp) * Wc)
                          +         wyp  * ldC2(slot_of(yp + 1) * Wc);
                float v3  = (1.0f - wyn) * ldC2(slot_of(yn) * Wc)
                          +         wyn  * ldC2(slot_of(yn + 1) * Wc);
                float xv  = tile[slot_of(i0 + r) * Wc + j];
                dst[(size_t)(r << 8)] = 0.25f * (v01 + v2 + v3) + tc * xv;
            }
        } else {
            // ============ direct-global exact (shift beyond window; ~6+ sigma) ============
            live = false;
            for (int r = 0; r < R; ++r) {
                const float gyr = gy_of(i0 + r);
                int yc, yp, yn; float wyc, wyp, wyn;
                coord_adj(gyr,      dy, Hc, yc, wyc);
                coord_adj(gyr,  s + dy, Hc, yp, wyp);
                coord_adj(gyr, -s + dy, Hc, yn, wyn);
                auto gS = [&](int y) -> float {
                    const float* rp = P + (size_t)y * Wc;
                    float a0 = rp[xp], a1 = rp[xp + 1];
                    float b0 = rp[xn], b1 = rp[xn + 1];
                    return (a0 + wxp * (a1 - a0)) + (b0 + wxn * (b1 - b0));
                };
                auto gC = [&](int y) -> float {
                    const float* rp = P + (size_t)y * Wc;
                    float a0 = rp[xc], a1 = rp[xc + 1];
                    return a0 + wxc * (a1 - a0);
                };
                float v01 = (1.0f - wyc) * gS(yc) + wyc * gS(yc + 1);
                float v2  = (1.0f - wyp) * gC(yp) + wyp * gC(yp + 1);
                float v3  = (1.0f - wyn) * gC(yn) + wyn * gC(yn + 1);
                float xv  = P[(size_t)(i0 + r) * Wc + j];
                dst[(size_t)(r << 8)] = 0.25f * (v01 + v2 + v3) + tc * xv;
            }
        }

        __syncthreads();   // drains vmcnt (strip landed) + barrier for slot reuse
    }
}

extern "C" void kernel_launch(void* const* d_in, const int* in_sizes, int n_in,
                              void* d_out, int out_size, void* d_ws, size_t ws_size,
                              hipStream_t stream)
{
    const float* x       = (const float*)d_in[0];
    const float* th_a    = (const float*)d_in[1];
    const float* th_bx   = (const float*)d_in[2];
    const float* th_by   = (const float*)d_in[3];
    const float* th_c    = (const float*)d_in[4];
    const float* base_gx = (const float*)d_in[5];
    const float* base_gy = (const float*)d_in[6];
    float* out = (float*)d_out;

    dim3 grid(Hc / (TB * R), Cc, Bc);   // (2, 64, 8) = 1024 blocks = 4/CU, compact
    dim3 block(Wc);
    remizov_ring<<<grid, block, 0, stream>>>(x, th_a, th_bx, th_by, th_c,
                                             base_gx, base_gy, out);
}

// Round 14
// 254.022 us; speedup vs baseline: 1.1884x; 1.0078x over previous
//
#include <hip/hip_runtime.h>

#define TAU 0.02f

constexpr int Bc = 8, Cc = 64, Hc = 256, Wc = 256;
constexpr int R   = 8;               // rows per pipeline step
constexpr int TB  = 16;              // steps per block (TB*R = 128 rows per block)
constexpr int RB  = 32;              // pow2 ring rows: 32 KB; grid gives 4 blocks/CU
constexpr int RBF = RB * Wc;         // 8192 floats (pow2)

__device__ __forceinline__ void coordf(float g, float shift, int n,
                                       int& i0, int& i1, float& w) {
    // exact reference semantics
    float p = (g + shift + 1.0f) * (0.5f * (float)(n - 1));
    p = fminf(fmaxf(p, 0.0f), (float)(n - 1));
    float f = floorf(p);
    w  = p - f;
    i0 = (int)f;
    i1 = min(i0 + 1, n - 1);
}

// clamp-adjusted pair: taps always (m, m+1); weight 1.0 when i0 clamped to n-1.
// Guarantees m in [0, n-2].
__device__ __forceinline__ void coord_adj(float g, float shift, int n,
                                          int& m, float& w) {
    int i0, i1; float ww;
    coordf(g, shift, n, i0, i1, ww);
    const bool top = (i0 == n - 1);
    m = top ? n - 2 : i0;
    w = top ? 1.0f  : ww;
}

__device__ __forceinline__ float gy_of(int i) {
    return fmaf((float)i, 2.0f / 255.0f, -1.0f);   // validated (prev session)
}

__device__ __forceinline__ float rdlane_f(float v, int lane) {
    return __int_as_float(__builtin_amdgcn_readlane(__float_as_int(v), lane));
}

__device__ __forceinline__ int slot_of(int row) {   // ring slot; RB pow2
    return row & (RB - 1);                          // two's-complement AND handles negatives
}

// async global -> LDS, 16 B per lane (one wave stages one full 256-float row)
__device__ __forceinline__ void gload_lds16(const float* g, float* l) {
    __builtin_amdgcn_global_load_lds(
        (const __attribute__((address_space(1))) void*)g,
        (__attribute__((address_space(3))) void*)l,
        16, 0, 0);
}

// T4 counted-vmcnt barrier: retire the (oldest) strip loads, keep this step's
// stores in flight. __syncthreads would be s_waitcnt vmcnt(0) lgkmcnt(0) -- the
// full store+load drain every step is the structural stall (guide §5 / T4).
__device__ __forceinline__ void barrier_keep8() {
    asm volatile("s_waitcnt vmcnt(8)" ::: "memory");
    __builtin_amdgcn_s_barrier();
    asm volatile("" ::: "memory");
}

__global__ __launch_bounds__(256, 4) void remizov_ring(
    const float* __restrict__ x,
    const float* __restrict__ th_a,
    const float* __restrict__ th_bx,
    const float* __restrict__ th_by,
    const float* __restrict__ th_c,
    const float* __restrict__ base_gx,
    const float* __restrict__ base_gy,
    float* __restrict__ out)
{
    __shared__ float tile[RBF];   // 32 KB ring

    const int j    = threadIdx.x;
    const int lane = j & 63;
    const int wv   = j >> 6;
    const int base = blockIdx.x * (TB * R);   // 0 or 128
    const int c    = blockIdx.y;
    const int b    = blockIdx.z;

    // ---- per-channel constants ----
    const float a  = log1pf(expf(th_a[c]));   // softplus
    const float s  = sqrtf(a * TAU + 1e-8f);
    const float dx = th_bx[c] * TAU;
    const float dy = th_by[c] * TAU;
    const float tc = th_c[c]  * TAU;

    // ---- x metadata: row-invariant, clamp-adjusted contiguous pairs ----
    const float gxv = base_gx[j];
    int xp, xn, xc; float wxp, wxn, wxc;
    coord_adj(gxv,  s + dx, Wc, xp, wxp);
    coord_adj(gxv, -s + dx, Wc, xn, wxn);
    coord_adj(gxv,      dx, Wc, xc, wxc);

    const size_t plane = (size_t)(b * Cc + c) * (size_t)(Hc * Wc);
    const float* __restrict__ P = x + plane;

    // ---- staging: nrows rows starting at row a (nrows % 4 == 0) ----
    // wave w stages row a+4k+w; 64 lanes x 16 B cover one full row per instr.
    auto stage = [&](int a, int nrows) {
        for (int k = 0; k < (nrows >> 2); ++k) {
            const int row  = a + 4 * k + wv;
            const int srow = min(max(row, 0), Hc - 1);     // clamp src; junk slots never read
            gload_lds16(P + (size_t)srow * Wc + lane * 4,
                        &tile[slot_of(row) * Wc + lane * 4]);
        }
    };

    stage(base - 4, 20);      // prologue: rows [base-4, base+15] (window for step 0)
    __syncthreads();          // full drain once at prologue is fine

    const int lane8 = j & 7;

    // ---- persistent rolling stream state (survives across steps) ----
    bool  live = false;
    int   l_acr = 0x7fffffff, l_apr = 0, l_anr = 0;
    int   oS = 0, oP = 0, oN = 0;
    float Sc0 = 0.f, Sc1 = 0.f, Wp0 = 0.f, Wp1 = 0.f, Wn0 = 0.f, Wn1 = 0.f;

    auto ldS2 = [&](int o) -> float {      // h+ + h- at ring float-offset o
        float a0 = tile[o + xp], a1 = tile[o + xp + 1];
        float b0 = tile[o + xn], b1 = tile[o + xn + 1];
        return (a0 + wxp * (a1 - a0)) + (b0 + wxn * (b1 - b0));
    };
    auto ldC2 = [&](int o) -> float {      // center column
        float a0 = tile[o + xc], a1 = tile[o + xc + 1];
        return a0 + wxc * (a1 - a0);
    };

    for (int t = 0; t < TB; ++t) {
        const int i0 = base + t * R;

        // issue next strip EARLY: these 2 loads/wave are the OLDEST vmcnt entries
        // this step; barrier_keep8 retires exactly them.
        // strip [i0+13, i0+20]; window reads stay <= i0+12 (disjoint, race-free)
        if (t < TB - 1) stage(i0 + 13, 8);

        // ---- per-lane exact y metadata: lane (j&7) owns row i0+(j&7) ----
        int   m_yc, m_yp, m_yn;
        float m_wc, m_wp, m_wn;
        {
            const float gyr = gy_of(i0 + lane8);
            coord_adj(gyr,      dy, Hc, m_yc, m_wc);
            coord_adj(gyr,  s + dy, Hc, m_yp, m_wp);
            coord_adj(gyr, -s + dy, Hc, m_yn, m_wn);
        }

        const int acr = __builtin_amdgcn_readlane(m_yc, 4) - (i0 + 4);
        const int apr = __builtin_amdgcn_readlane(m_yp, 4) - (i0 + 4);
        const int anr = __builtin_amdgcn_readlane(m_yn, 4) - (i0 + 4);
        const float wc = rdlane_f(m_wc, 4);
        const float wp = rdlane_f(m_wp, 4);
        const float wn = rdlane_f(m_wn, 4);

        // conformity (uniform stencil); delta bound keeps every read (incl the
        // r=7 prefetch at row i0+9+delta) inside window [i0-4, i0+12]
        bool okc = (m_yc == i0 + lane8 + acr) &&
                   (m_yp == i0 + lane8 + apr) &&
                   (m_yn == i0 + lane8 + anr);
        const bool okd = (acr >= -4 && acr <= 3) &&
                         (apr >= -4 && apr <= 3) &&
                         (anr >= -4 && anr <= 3);
        // exact-ring coverage: taps m, m+1 within [i0-4, i0+12]
        bool okw = (m_yc >= i0 - 4) && (m_yc <= i0 + 11) &&
                   (m_yp >= i0 - 4) && (m_yp <= i0 + 11) &&
                   (m_yn >= i0 - 4) && (m_yn <= i0 + 11);
        const unsigned long long cm = __ballot(okc);
        const unsigned long long wm = __ballot(okw);

        float* __restrict__ dst = out + plane + (size_t)i0 * Wc + j;

        if (cm == 0xFFFFFFFFFFFFFFFFull && okd) {
            // ============ fast uniform path: persistent rolling streams ============
            if (!live || acr != l_acr || apr != l_apr || anr != l_anr) {
                l_acr = acr; l_apr = apr; l_anr = anr;
                oS = slot_of(i0 + acr) * Wc;
                Sc0 = ldS2(oS); oS = (oS + Wc) & (RBF - 1); Sc1 = ldS2(oS);
                oP = slot_of(i0 + apr) * Wc;
                Wp0 = ldC2(oP); oP = (oP + Wc) & (RBF - 1); Wp1 = ldC2(oP);
                oN = slot_of(i0 + anr) * Wc;
                Wn0 = ldC2(oN); oN = (oN + Wc) & (RBF - 1); Wn1 = ldC2(oN);
                live = true;
            }
            int oX = slot_of(i0) * Wc;

#pragma unroll
            for (int r = 0; r < R; ++r) {
                float v01 = Sc0 + wc * (Sc1 - Sc0);
                float v2  = Wp0 + wp * (Wp1 - Wp0);
                float v3  = Wn0 + wn * (Wn1 - Wn0);
                float xv  = tile[oX + j];
                dst[(size_t)(r << 8)] = 0.25f * (v01 + v2 + v3) + tc * xv;
                oX = (oX + Wc) & (RBF - 1);
                // advance EVERY row (incl r=7): leaves state = next step's warmup
                Sc0 = Sc1; oS = (oS + Wc) & (RBF - 1); Sc1 = ldS2(oS);
                Wp0 = Wp1; oP = (oP + Wc) & (RBF - 1); Wp1 = ldC2(oP);
                Wn0 = Wn1; oN = (oN + Wc) & (RBF - 1); Wn1 = ldC2(oN);
            }
        } else if (wm == 0xFFFFFFFFFFFFFFFFull) {
            // ============ exact ring path (borders / floor flips) ============
            live = false;
            for (int r = 0; r < R; ++r) {
                const float gyr = gy_of(i0 + r);
                int yc, yp, yn; float wyc, wyp, wyn;
                coord_adj(gyr,      dy, Hc, yc, wyc);
                coord_adj(gyr,  s + dy, Hc, yp, wyp);
                coord_adj(gyr, -s + dy, Hc, yn, wyn);
                float v01 = (1.0f - wyc) * ldS2(slot_of(yc) * Wc)
                          +         wyc  * ldS2(slot_of(yc + 1) * Wc);
                float v2  = (1.0f - wyp) * ldC2(slot_of(yp) * Wc)
                          +         wyp  * ldC2(slot_of(yp + 1) * Wc);
                float v3  = (1.0f - wyn) * ldC2(slot_of(yn) * Wc)
                          +         wyn  * ldC2(slot_of(yn + 1) * Wc);
                float xv  = tile[slot_of(i0 + r) * Wc + j];
                dst[(size_t)(r << 8)] = 0.25f * (v01 + v2 + v3) + tc * xv;
            }
        } else {
            // ============ direct-global exact (shift beyond window; ~6+ sigma) ============
            live = false;
            for (int r = 0; r < R; ++r) {
                const float gyr = gy_of(i0 + r);
                int yc, yp, yn; float wyc, wyp, wyn;
                coord_adj(gyr,      dy, Hc, yc, wyc);
                coord_adj(gyr,  s + dy, Hc, yp, wyp);
                coord_adj(gyr, -s + dy, Hc, yn, wyn);
                auto gS = [&](int y) -> float {
                    const float* rp = P + (size_t)y * Wc;
                    float a0 = rp[xp], a1 = rp[xp + 1];
                    float b0 = rp[xn], b1 = rp[xn + 1];
                    return (a0 + wxp * (a1 - a0)) + (b0 + wxn * (b1 - b0));
                };
                auto gC = [&](int y) -> float {
                    const float* rp = P + (size_t)y * Wc;
                    float a0 = rp[xc], a1 = rp[xc + 1];
                    return a0 + wxc * (a1 - a0);
                };
                float v01 = (1.0f - wyc) * gS(yc) + wyc * gS(yc + 1);
                float v2  = (1.0f - wyp) * gC(yp) + wyp * gC(yp + 1);
                float v3  = (1.0f - wyn) * gC(yn) + wyn * gC(yn + 1);
                float xv  = P[(size_t)(i0 + r) * Wc + j];
                dst[(size_t)(r << 8)] = 0.25f * (v01 + v2 + v3) + tc * xv;
            }
        }

        // counted-vmcnt barrier (T4): strip loads (oldest) retired, stores stay in flight
        barrier_keep8();
    }
}

extern "C" void kernel_launch(void* const* d_in, const int* in_sizes, int n_in,
                              void* d_out, int out_size, void* d_ws, size_t ws_size,
                              hipStream_t stream)
{
    const float* x       = (const float*)d_in[0];
    const float* th_a    = (const float*)d_in[1];
    const float* th_bx   = (const float*)d_in[2];
    const float* th_by   = (const float*)d_in[3];
    const float* th_c    = (const float*)d_in[4];
    const float* base_gx = (const float*)d_in[5];
    const float* base_gy = (const float*)d_in[6];
    float* out = (float*)d_out;

    dim3 grid(Hc / (TB * R), Cc, Bc);   // (2, 64, 8) = 1024 blocks = 4/CU, compact
    dim3 block(Wc);
    remizov_ring<<<grid, block, 0, stream>>>(x, th_a, th_bx, th_by, th_c,
                                             base_gx, base_gy, out);
}